// Round 1
// baseline (128.251 us; speedup 1.0000x reference)
//
#include <hip/hip_runtime.h>

// lambda-return (reverse scan over T=16), one thread per 4 columns.
// target[t] = reward[t] + discount[t] * (LAM*acc + (1-LAM)*value[t+1]),
// acc initialized to value[T-1], t = T-2 .. 0.

constexpr int   T_STEPS = 16;
constexpr float LAM     = 0.95f;

__global__ __launch_bounds__(256)
void ImagBehavior_67284957659345_kernel(const float4* __restrict__ reward,
                                        const float4* __restrict__ value,
                                        const float4* __restrict__ discount,
                                        float4* __restrict__ out,
                                        int Bv /* = B/4 */) {
    int idx = blockIdx.x * blockDim.x + threadIdx.x;
    if (idx >= Bv) return;

    // bootstrap: acc = value[T-1]; also serves as v_next for t = T-2
    float4 vnext = value[(T_STEPS - 1) * Bv + idx];
    float4 acc   = vnext;

#pragma unroll
    for (int t = T_STEPS - 2; t >= 0; --t) {
        float4 r = reward[t * Bv + idx];
        float4 d = discount[t * Bv + idx];

        acc.x = r.x + d.x * (LAM * acc.x + (1.0f - LAM) * vnext.x);
        acc.y = r.y + d.y * (LAM * acc.y + (1.0f - LAM) * vnext.y);
        acc.z = r.z + d.z * (LAM * acc.z + (1.0f - LAM) * vnext.z);
        acc.w = r.w + d.w * (LAM * acc.w + (1.0f - LAM) * vnext.w);

        out[t * Bv + idx] = acc;

        if (t > 0) {
            vnext = value[t * Bv + idx];  // value[(t-1)+1] for next iteration
        }
    }
}

extern "C" void kernel_launch(void* const* d_in, const int* in_sizes, int n_in,
                              void* d_out, int out_size, void* d_ws, size_t ws_size,
                              hipStream_t stream) {
    const float4* reward   = (const float4*)d_in[0];
    const float4* value    = (const float4*)d_in[1];
    const float4* discount = (const float4*)d_in[2];
    float4*       out      = (float4*)d_out;

    const int B  = in_sizes[0] / T_STEPS;  // 524288
    const int Bv = B / 4;                  // 131072 float4 columns

    const int block = 256;
    const int grid  = (Bv + block - 1) / block;

    ImagBehavior_67284957659345_kernel<<<grid, block, 0, stream>>>(
        reward, value, discount, out, Bv);
}

// Round 2
// 128.010 us; speedup vs baseline: 1.0019x; 1.0019x over previous
//
#include <hip/hip_runtime.h>

// lambda-return reverse scan, T=16 rows x B=524288 cols, fp32.
// Strategy: one thread per 2 columns (float2), FULL register prefetch of all
// 46 loads before the serial FMA chain, 1024 blocks -> 16 waves/CU.
// __launch_bounds__(256,4): cap VGPR <=128 so we keep 4 waves/SIMD.

constexpr int   T_STEPS = 16;
constexpr float LAM     = 0.95f;

__global__ __launch_bounds__(256, 4)
void ImagBehavior_67284957659345_kernel(const float2* __restrict__ reward,
                                        const float2* __restrict__ value,
                                        const float2* __restrict__ discount,
                                        float2* __restrict__ out,
                                        int Bv /* = B/2 */) {
    int idx = blockIdx.x * blockDim.x + threadIdx.x;
    if (idx >= Bv) return;

    // ---- prefetch phase: all loads independent, issued back-to-back in
    // consumption order (v15 first, then t=14..0) so compute can start as
    // soon as the oldest loads land while the rest stay in flight.
    float2 r[T_STEPS - 1];   // reward rows 0..14
    float2 d[T_STEPS - 1];   // discount rows 0..14
    float2 v[T_STEPS];       // value rows 1..15 used (v[0] never read)

    v[T_STEPS - 1] = value[(T_STEPS - 1) * Bv + idx];
#pragma unroll
    for (int t = T_STEPS - 2; t >= 0; --t) {
        r[t] = reward[t * Bv + idx];
        d[t] = discount[t * Bv + idx];
        if (t >= 1) v[t] = value[t * Bv + idx];
    }

    // ---- serial chain (15 x 3 FMA per lane-element, trivial)
    float2 acc = v[T_STEPS - 1];
#pragma unroll
    for (int t = T_STEPS - 2; t >= 0; --t) {
        const float2 vn = v[t + 1];
        acc.x = r[t].x + d[t].x * (LAM * acc.x + (1.0f - LAM) * vn.x);
        acc.y = r[t].y + d[t].y * (LAM * acc.y + (1.0f - LAM) * vn.y);
        out[t * Bv + idx] = acc;  // fire-and-forget store
    }
}

extern "C" void kernel_launch(void* const* d_in, const int* in_sizes, int n_in,
                              void* d_out, int out_size, void* d_ws, size_t ws_size,
                              hipStream_t stream) {
    const float2* reward   = (const float2*)d_in[0];
    const float2* value    = (const float2*)d_in[1];
    const float2* discount = (const float2*)d_in[2];
    float2*       out      = (float2*)d_out;

    const int B  = in_sizes[0] / T_STEPS;  // 524288
    const int Bv = B / 2;                  // 262144 float2 columns

    const int block = 256;
    const int grid  = (Bv + block - 1) / block;  // 1024 blocks

    ImagBehavior_67284957659345_kernel<<<grid, block, 0, stream>>>(
        reward, value, discount, out, Bv);
}